// Round 5
// baseline (193.551 us; speedup 1.0000x reference)
//
#include <hip/hip_runtime.h>
#include <math.h>

#define LL 16384
#define Dm 768
#define Hm 1024

#define ATT_B 512          // attention blocks; 4 waves/block, 8 rows/wave
#define GI_B  192          // gi blocks, 16 rows each (3072 total)
#define GH_B  192          // gh blocks, 16 rows each (3072 total)
#define NP    2048         // attention partials (one per wave)
#define MID_B 64           // k_mid blocks, 32 partials each -> 64 L2 partials

// ws layout (float offsets)
#define WS_GI 0                            // 3072
#define WS_GH 3072                         // 3072
#define WS_PM 6144                         // 2048 wave-local maxes
#define WS_PS 8192                         // 2048 wave-local exp-sums
#define WS_PV 10240                        // 2048*1024 partial vectors
#define WS_M2 (10240 + 2048*1024)          // 64
#define WS_S2 (WS_M2 + 64)                 // 64
#define WS_V2 (WS_S2 + 64)                 // 64*1024

__device__ __forceinline__ float dot4(float4 a, float4 b) {
    return a.x*b.x + a.y*b.y + a.z*b.z + a.w*b.w;
}

// K1: blocks [0,512):    attention — each WAVE independently: 8 dots + local
//                        softmax + weighted hidden sum. No LDS, no barriers.
//     blocks [512,704):  gi[k] = text_v . W_ih[k][off:off+768] + b_ih[k]
//     blocks [704,896):  gh[k] = h . W_hh[k] + b_hh[k]
__global__ __launch_bounds__(256) void k_main(
    const float* __restrict__ text_v, const float* __restrict__ result,
    const float* __restrict__ text_s, const float* __restrict__ hidden_s,
    const float* __restrict__ W_ih, const float* __restrict__ W_hh,
    const float* __restrict__ b_ih, const float* __restrict__ b_hh,
    float* __restrict__ ws)
{
    const int b    = blockIdx.x;
    const int tid  = threadIdx.x;
    const int lane = tid & 63;
    const int wv   = tid >> 6;

    if (b < ATT_B) {
        const int wid = b*4 + wv;              // 0..2047
        const int r0  = wid*8;

        float4 tv0 = *(const float4*)(text_v + 4*lane);
        float4 tv1 = *(const float4*)(text_v + 4*lane + 256);
        float4 tv2 = *(const float4*)(text_v + 4*lane + 512);

        // ---- dots: batch all 24 row-fragment loads, then reduce ----
        float4 x[8][3];
        #pragma unroll
        for (int i = 0; i < 8; ++i) {
            const float* p = text_s + (size_t)(r0 + i)*Dm + 4*lane;
            x[i][0] = *(const float4*)(p);
            x[i][1] = *(const float4*)(p + 256);
            x[i][2] = *(const float4*)(p + 512);
        }
        float pd[8];
        #pragma unroll
        for (int i = 0; i < 8; ++i)
            pd[i] = dot4(x[i][0], tv0) + dot4(x[i][1], tv1) + dot4(x[i][2], tv2);
        #pragma unroll
        for (int i = 0; i < 8; ++i) {
            #pragma unroll
            for (int o = 32; o; o >>= 1) pd[i] += __shfl_xor(pd[i], o);
        }

        // ---- wave-local softmax weights ----
        float m = pd[0];
        #pragma unroll
        for (int i = 1; i < 8; ++i) m = fmaxf(m, pd[i]);
        float w[8], s = 0.f;
        #pragma unroll
        for (int i = 0; i < 8; ++i) { w[i] = expf(pd[i] - m); s += w[i]; }

        // ---- weighted hidden sum: 2 chunks x 16 float4 in flight ----
        float4 acc[4] = {{0,0,0,0},{0,0,0,0},{0,0,0,0},{0,0,0,0}};
        #pragma unroll
        for (int c = 0; c < 2; ++c) {
            float4 hv[4][4];
            #pragma unroll
            for (int j = 0; j < 4; ++j) {
                const float* p = hidden_s + (size_t)(r0 + c*4 + j)*Hm + 4*lane;
                #pragma unroll
                for (int k = 0; k < 4; ++k) hv[j][k] = *(const float4*)(p + 256*k);
            }
            #pragma unroll
            for (int j = 0; j < 4; ++j) {
                const float wj = w[c*4 + j];
                #pragma unroll
                for (int k = 0; k < 4; ++k) {
                    acc[k].x += wj*hv[j][k].x; acc[k].y += wj*hv[j][k].y;
                    acc[k].z += wj*hv[j][k].z; acc[k].w += wj*hv[j][k].w;
                }
            }
        }
        #pragma unroll
        for (int k = 0; k < 4; ++k)
            *(float4*)(ws + WS_PV + (size_t)wid*1024 + 4*lane + 256*k) = acc[k];
        if (lane == 0) {
            ws[WS_PM + wid] = m;
            ws[WS_PS + wid] = s;
        }
    } else if (b < ATT_B + GI_B) {
        const int gb  = b - ATT_B;             // 0..191
        const int off = (result[0] >= 0.5f) ? 0 : Dm;
        float4 tv0 = *(const float4*)(text_v + 4*lane);
        float4 tv1 = *(const float4*)(text_v + 4*lane + 256);
        float4 tv2 = *(const float4*)(text_v + 4*lane + 512);
        const int kbase = gb*16 + wv*4;
        float4 x[4][3];
        #pragma unroll
        for (int i = 0; i < 4; ++i) {
            const float* p = W_ih + (size_t)(kbase + i)*(2*Dm) + off + 4*lane;
            x[i][0] = *(const float4*)(p);
            x[i][1] = *(const float4*)(p + 256);
            x[i][2] = *(const float4*)(p + 512);
        }
        #pragma unroll
        for (int i = 0; i < 4; ++i) {
            float s = dot4(x[i][0], tv0) + dot4(x[i][1], tv1) + dot4(x[i][2], tv2);
            #pragma unroll
            for (int o = 32; o; o >>= 1) s += __shfl_xor(s, o);
            const int k = kbase + i;
            if (lane == 0) ws[WS_GI + k] = s + b_ih[k];
        }
    } else {
        const int hb = b - ATT_B - GI_B;       // 0..191
        const float* h = hidden_s + (size_t)(LL - 1)*Hm;
        float4 h0 = *(const float4*)(h + 4*lane);
        float4 h1 = *(const float4*)(h + 4*lane + 256);
        float4 h2 = *(const float4*)(h + 4*lane + 512);
        float4 h3 = *(const float4*)(h + 4*lane + 768);
        const int kbase = hb*16 + wv*4;
        float4 x[4][4];
        #pragma unroll
        for (int i = 0; i < 4; ++i) {
            const float* p = W_hh + (size_t)(kbase + i)*Hm + 4*lane;
            x[i][0] = *(const float4*)(p);
            x[i][1] = *(const float4*)(p + 256);
            x[i][2] = *(const float4*)(p + 512);
            x[i][3] = *(const float4*)(p + 768);
        }
        #pragma unroll
        for (int i = 0; i < 4; ++i) {
            float s = dot4(x[i][0], h0) + dot4(x[i][1], h1)
                    + dot4(x[i][2], h2) + dot4(x[i][3], h3);
            #pragma unroll
            for (int o = 32; o; o >>= 1) s += __shfl_xor(s, o);
            const int k = kbase + i;
            if (lane == 0) ws[WS_GH + k] = s + b_hh[k];
        }
    }
}

// K2: reduce 2048 partials -> 64, rescaling by exp(m_p - chunk max)
__global__ __launch_bounds__(256) void k_mid(float* __restrict__ ws) {
    __shared__ float sm[32];
    __shared__ float sc[32];
    const int b  = blockIdx.x;                 // 0..63
    const int t  = threadIdx.x;
    const int p0 = b * 32;
    if (t < 32) sm[t] = ws[WS_PM + p0 + t];
    __syncthreads();
    float m = sm[0];
    #pragma unroll
    for (int r = 1; r < 32; ++r) m = fmaxf(m, sm[r]);
    if (t < 32) sc[t] = expf(sm[t] - m);
    __syncthreads();

    float4 acc = {0.f, 0.f, 0.f, 0.f};
    #pragma unroll
    for (int c = 0; c < 4; ++c) {
        float4 hv[8];
        #pragma unroll
        for (int r = 0; r < 8; ++r)
            hv[r] = *(const float4*)(ws + WS_PV + (size_t)(p0 + c*8 + r)*1024 + 4*t);
        #pragma unroll
        for (int r = 0; r < 8; ++r) {
            const float w = sc[c*8 + r];
            acc.x += w*hv[r].x; acc.y += w*hv[r].y;
            acc.z += w*hv[r].z; acc.w += w*hv[r].w;
        }
    }
    *(float4*)(ws + WS_V2 + (size_t)b*1024 + 4*t) = acc;
    if (t == 0) {
        float s = 0.f;
        #pragma unroll
        for (int r = 0; r < 32; ++r) s += sc[r] * ws[WS_PS + p0 + r];
        ws[WS_M2 + b] = m;
        ws[WS_S2 + b] = s;
    }
}

// K3: final combine (64 partials) + score + GRU
__global__ __launch_bounds__(1024) void k_final(
    const float* __restrict__ text_v, const float* __restrict__ hidden_s,
    const float* __restrict__ score_W, const float* __restrict__ score_b,
    float* __restrict__ ws, float* __restrict__ out)
{
    __shared__ float sred[16];
    const int tid = threadIdx.x;                // column 0..1023
    float mbuf[8], M;
    #pragma unroll
    for (int i = 0; i < 8; ++i) mbuf[i] = ws[WS_M2 + i*8];      // stride batch 1/8
    M = ws[WS_M2];
    #pragma unroll
    for (int r = 1; r < 64; ++r) M = fmaxf(M, ws[WS_M2 + r]);
    (void)mbuf;
    float S = 0.f, a = 0.f;
    #pragma unroll
    for (int c = 0; c < 8; ++c) {
        float scl[8], vv[8];
        #pragma unroll
        for (int r = 0; r < 8; ++r) {
            scl[r] = expf(ws[WS_M2 + c*8 + r] - M);
            vv[r]  = ws[WS_V2 + (c*8 + r)*1024 + tid];
        }
        #pragma unroll
        for (int r = 0; r < 8; ++r) {
            S += scl[r] * ws[WS_S2 + c*8 + r];
            a += scl[r] * vv[r];
        }
    }
    a /= S;                                     // attn_h[tid]
    // score = text_v . sW[0:768] + attn_h . sW[768:1792] + b
    float sp = a * score_W[Dm + tid];
    if (tid < Dm) sp += text_v[tid] * score_W[tid];
    #pragma unroll
    for (int o = 32; o; o >>= 1) sp += __shfl_xor(sp, o);
    if ((tid & 63) == 0) sred[tid >> 6] = sp;
    __syncthreads();
    if (tid == 0) {
        float s = score_b[0];
        #pragma unroll
        for (int i = 0; i < 16; ++i) s += sred[i];
        out[0] = s;
    }
    // GRU
    const float gi_r = ws[WS_GI + tid];
    const float gi_z = ws[WS_GI + 1024 + tid];
    const float gi_n = ws[WS_GI + 2048 + tid];
    const float gh_r = ws[WS_GH + tid];
    const float gh_z = ws[WS_GH + 1024 + tid];
    const float gh_n = ws[WS_GH + 2048 + tid];
    const float hprev = hidden_s[(size_t)(LL - 1)*Hm + tid];
    const float r = 1.f / (1.f + expf(-(gi_r + gh_r)));
    const float z = 1.f / (1.f + expf(-(gi_z + gh_z)));
    const float n = tanhf(gi_n + r*gh_n);
    out[1 + tid] = (1.f - z)*n + z*hprev;
}

extern "C" void kernel_launch(void* const* d_in, const int* in_sizes, int n_in,
                              void* d_out, int out_size, void* d_ws, size_t ws_size,
                              hipStream_t stream) {
    const float* text_v   = (const float*)d_in[0];
    const float* result   = (const float*)d_in[1];
    const float* text_s   = (const float*)d_in[2];
    const float* hidden_s = (const float*)d_in[3];
    const float* W_ih     = (const float*)d_in[4];
    const float* W_hh     = (const float*)d_in[5];
    const float* b_ih     = (const float*)d_in[6];
    const float* b_hh     = (const float*)d_in[7];
    const float* score_W  = (const float*)d_in[8];
    const float* score_b  = (const float*)d_in[9];
    float* out = (float*)d_out;
    float* ws  = (float*)d_ws;

    k_main <<<ATT_B + GI_B + GH_B, 256, 0, stream>>>(
        text_v, result, text_s, hidden_s, W_ih, W_hh, b_ih, b_hh, ws);
    k_mid  <<<MID_B, 256, 0, stream>>>(ws);
    k_final<<<1, 1024, 0, stream>>>(text_v, hidden_s, score_W, score_b, ws, out);
}

// Round 6
// 188.800 us; speedup vs baseline: 1.0252x; 1.0252x over previous
//
#include <hip/hip_runtime.h>
#include <math.h>

#define LL 16384
#define Dm 768
#define Hm 1024

#define ATT_B 1024         // attention blocks; 4 waves/block, 4 rows/wave (16 rows/block)
#define GI_B  192          // gi blocks, 16 rows each (3072 total)
#define GH_B  192          // gh blocks, 16 rows each (3072 total)
#define MID_B 32           // k_mid blocks, 32 partials each -> 32 L2 partials

// ws layout (float offsets)
#define WS_GI 0                            // 3072
#define WS_GH 3072                         // 3072
#define WS_PM 6144                         // 1024 block maxes
#define WS_PS 7168                         // 1024 block exp-sums
#define WS_PV 8192                         // 1024*1024 partial vectors (4 MB)
#define WS_M2 (8192 + 1024*1024)           // 32
#define WS_S2 (WS_M2 + 32)                 // 32
#define WS_V2 (WS_S2 + 32)                 // 32*1024

__device__ __forceinline__ float dot4(float4 a, float4 b) {
    return a.x*b.x + a.y*b.y + a.z*b.z + a.w*b.w;
}

// K1: blocks [0,1024):       attention — wave owns 4 rows: dots + wave-local
//                            softmax + weighted hidden sum; ONE barrier at end
//                            to combine the block's 4 wave-partials in LDS.
//     blocks [1024,1216):    gi[k] = text_v . W_ih[k][off:off+768] + b_ih[k]
//     blocks [1216,1408):    gh[k] = h . W_hh[k] + b_hh[k]
__global__ __launch_bounds__(256, 4) void k_main(
    const float* __restrict__ text_v, const float* __restrict__ result,
    const float* __restrict__ text_s, const float* __restrict__ hidden_s,
    const float* __restrict__ W_ih, const float* __restrict__ W_hh,
    const float* __restrict__ b_ih, const float* __restrict__ b_hh,
    float* __restrict__ ws)
{
    const int b    = blockIdx.x;
    const int tid  = threadIdx.x;
    const int lane = tid & 63;
    const int wv   = tid >> 6;

    if (b < ATT_B) {
        __shared__ float sacc[4][1024];        // 16 KB
        __shared__ float smx[4], ssm[4];
        const int r0 = b*16 + wv*4;            // wave's first row

        float4 tv0 = *(const float4*)(text_v + 4*lane);
        float4 tv1 = *(const float4*)(text_v + 4*lane + 256);
        float4 tv2 = *(const float4*)(text_v + 4*lane + 512);

        // ---- batch ALL dot loads + first hidden chunk (20 f4 in flight) ----
        float4 x[4][3];
        #pragma unroll
        for (int i = 0; i < 4; ++i) {
            const float* p = text_s + (size_t)(r0 + i)*Dm + 4*lane;
            x[i][0] = *(const float4*)(p);
            x[i][1] = *(const float4*)(p + 256);
            x[i][2] = *(const float4*)(p + 512);
        }
        float4 hv0[2][4];                      // rows r0, r0+1 (full 1024 cols)
        #pragma unroll
        for (int j = 0; j < 2; ++j) {
            const float* p = hidden_s + (size_t)(r0 + j)*Hm + 4*lane;
            #pragma unroll
            for (int k = 0; k < 4; ++k) hv0[j][k] = *(const float4*)(p + 256*k);
        }

        // ---- dots + butterfly reduce (all lanes get results) ----
        float pd[4];
        #pragma unroll
        for (int i = 0; i < 4; ++i)
            pd[i] = dot4(x[i][0], tv0) + dot4(x[i][1], tv1) + dot4(x[i][2], tv2);
        #pragma unroll
        for (int i = 0; i < 4; ++i) {
            #pragma unroll
            for (int o = 32; o; o >>= 1) pd[i] += __shfl_xor(pd[i], o);
        }

        // ---- wave-local softmax weights ----
        float m = fmaxf(fmaxf(pd[0], pd[1]), fmaxf(pd[2], pd[3]));
        float w[4], s = 0.f;
        #pragma unroll
        for (int i = 0; i < 4; ++i) { w[i] = expf(pd[i] - m); s += w[i]; }

        // ---- second hidden chunk in flight, then FMA both ----
        float4 hv1[2][4];                      // rows r0+2, r0+3
        #pragma unroll
        for (int j = 0; j < 2; ++j) {
            const float* p = hidden_s + (size_t)(r0 + 2 + j)*Hm + 4*lane;
            #pragma unroll
            for (int k = 0; k < 4; ++k) hv1[j][k] = *(const float4*)(p + 256*k);
        }
        float4 acc[4];
        #pragma unroll
        for (int k = 0; k < 4; ++k) {
            acc[k].x = w[0]*hv0[0][k].x + w[1]*hv0[1][k].x;
            acc[k].y = w[0]*hv0[0][k].y + w[1]*hv0[1][k].y;
            acc[k].z = w[0]*hv0[0][k].z + w[1]*hv0[1][k].z;
            acc[k].w = w[0]*hv0[0][k].w + w[1]*hv0[1][k].w;
        }
        #pragma unroll
        for (int k = 0; k < 4; ++k) {
            acc[k].x += w[2]*hv1[0][k].x + w[3]*hv1[1][k].x;
            acc[k].y += w[2]*hv1[0][k].y + w[3]*hv1[1][k].y;
            acc[k].z += w[2]*hv1[0][k].z + w[3]*hv1[1][k].z;
            acc[k].w += w[2]*hv1[0][k].w + w[3]*hv1[1][k].w;
        }

        // ---- single end-of-block combine ----
        #pragma unroll
        for (int k = 0; k < 4; ++k)
            *(float4*)&sacc[wv][4*lane + 256*k] = acc[k];
        if (lane == 0) { smx[wv] = m; ssm[wv] = s; }
        __syncthreads();

        const float M = fmaxf(fmaxf(smx[0], smx[1]), fmaxf(smx[2], smx[3]));
        float sc0 = expf(smx[0] - M), sc1 = expf(smx[1] - M);
        float sc2 = expf(smx[2] - M), sc3 = expf(smx[3] - M);
        float4 v0 = *(const float4*)&sacc[0][4*tid];
        float4 v1 = *(const float4*)&sacc[1][4*tid];
        float4 v2 = *(const float4*)&sacc[2][4*tid];
        float4 v3 = *(const float4*)&sacc[3][4*tid];
        float4 r;
        r.x = sc0*v0.x + sc1*v1.x + sc2*v2.x + sc3*v3.x;
        r.y = sc0*v0.y + sc1*v1.y + sc2*v2.y + sc3*v3.y;
        r.z = sc0*v0.z + sc1*v1.z + sc2*v2.z + sc3*v3.z;
        r.w = sc0*v0.w + sc1*v1.w + sc2*v2.w + sc3*v3.w;
        *(float4*)(ws + WS_PV + (size_t)b*1024 + 4*tid) = r;
        if (tid == 0) {
            ws[WS_PM + b] = M;
            ws[WS_PS + b] = sc0*ssm[0] + sc1*ssm[1] + sc2*ssm[2] + sc3*ssm[3];
        }
    } else if (b < ATT_B + GI_B) {
        const int gb  = b - ATT_B;             // 0..191
        const int off = (result[0] >= 0.5f) ? 0 : Dm;
        float4 tv0 = *(const float4*)(text_v + 4*lane);
        float4 tv1 = *(const float4*)(text_v + 4*lane + 256);
        float4 tv2 = *(const float4*)(text_v + 4*lane + 512);
        const int kbase = gb*16 + wv*4;
        float4 x[4][3];
        #pragma unroll
        for (int i = 0; i < 4; ++i) {
            const float* p = W_ih + (size_t)(kbase + i)*(2*Dm) + off + 4*lane;
            x[i][0] = *(const float4*)(p);
            x[i][1] = *(const float4*)(p + 256);
            x[i][2] = *(const float4*)(p + 512);
        }
        #pragma unroll
        for (int i = 0; i < 4; ++i) {
            float s = dot4(x[i][0], tv0) + dot4(x[i][1], tv1) + dot4(x[i][2], tv2);
            #pragma unroll
            for (int o = 32; o; o >>= 1) s += __shfl_xor(s, o);
            const int k = kbase + i;
            if (lane == 0) ws[WS_GI + k] = s + b_ih[k];
        }
    } else {
        const int hb = b - ATT_B - GI_B;       // 0..191
        const float* h = hidden_s + (size_t)(LL - 1)*Hm;
        float4 h0 = *(const float4*)(h + 4*lane);
        float4 h1 = *(const float4*)(h + 4*lane + 256);
        float4 h2 = *(const float4*)(h + 4*lane + 512);
        float4 h3 = *(const float4*)(h + 4*lane + 768);
        const int kbase = hb*16 + wv*4;
        float4 x[4][4];
        #pragma unroll
        for (int i = 0; i < 4; ++i) {
            const float* p = W_hh + (size_t)(kbase + i)*Hm + 4*lane;
            x[i][0] = *(const float4*)(p);
            x[i][1] = *(const float4*)(p + 256);
            x[i][2] = *(const float4*)(p + 512);
            x[i][3] = *(const float4*)(p + 768);
        }
        #pragma unroll
        for (int i = 0; i < 4; ++i) {
            float s = dot4(x[i][0], h0) + dot4(x[i][1], h1)
                    + dot4(x[i][2], h2) + dot4(x[i][3], h3);
            #pragma unroll
            for (int o = 32; o; o >>= 1) s += __shfl_xor(s, o);
            const int k = kbase + i;
            if (lane == 0) ws[WS_GH + k] = s + b_hh[k];
        }
    }
}

// K2: reduce 1024 partials -> 32, rescaling by exp(m_p - chunk max)
__global__ __launch_bounds__(256) void k_mid(float* __restrict__ ws) {
    __shared__ float sm[32];
    __shared__ float sc[32];
    const int b  = blockIdx.x;                 // 0..31
    const int t  = threadIdx.x;
    const int p0 = b * 32;
    if (t < 32) sm[t] = ws[WS_PM + p0 + t];
    __syncthreads();
    float m = sm[0];
    #pragma unroll
    for (int r = 1; r < 32; ++r) m = fmaxf(m, sm[r]);
    if (t < 32) sc[t] = expf(sm[t] - m);
    __syncthreads();

    float4 acc = {0.f, 0.f, 0.f, 0.f};
    #pragma unroll
    for (int c = 0; c < 4; ++c) {
        float4 hv[8];
        #pragma unroll
        for (int r = 0; r < 8; ++r)
            hv[r] = *(const float4*)(ws + WS_PV + (size_t)(p0 + c*8 + r)*1024 + 4*t);
        #pragma unroll
        for (int r = 0; r < 8; ++r) {
            const float w = sc[c*8 + r];
            acc.x += w*hv[r].x; acc.y += w*hv[r].y;
            acc.z += w*hv[r].z; acc.w += w*hv[r].w;
        }
    }
    *(float4*)(ws + WS_V2 + (size_t)b*1024 + 4*t) = acc;
    if (t == 0) {
        float s = 0.f;
        #pragma unroll
        for (int r = 0; r < 32; ++r) s += sc[r] * ws[WS_PS + p0 + r];
        ws[WS_M2 + b] = m;
        ws[WS_S2 + b] = s;
    }
}

// K3: final combine (32 partials) + score + GRU
__global__ __launch_bounds__(1024) void k_final(
    const float* __restrict__ text_v, const float* __restrict__ hidden_s,
    const float* __restrict__ score_W, const float* __restrict__ score_b,
    float* __restrict__ ws, float* __restrict__ out)
{
    __shared__ float sred[16];
    const int tid = threadIdx.x;                // column 0..1023
    float M = ws[WS_M2];
    #pragma unroll
    for (int r = 1; r < 32; ++r) M = fmaxf(M, ws[WS_M2 + r]);
    float S = 0.f, a = 0.f;
    #pragma unroll
    for (int c = 0; c < 4; ++c) {
        float scl[8], vv[8];
        #pragma unroll
        for (int r = 0; r < 8; ++r) {
            scl[r] = expf(ws[WS_M2 + c*8 + r] - M);
            vv[r]  = ws[WS_V2 + (c*8 + r)*1024 + tid];
        }
        #pragma unroll
        for (int r = 0; r < 8; ++r) {
            S += scl[r] * ws[WS_S2 + c*8 + r];
            a += scl[r] * vv[r];
        }
    }
    a /= S;                                     // attn_h[tid]
    // score = text_v . sW[0:768] + attn_h . sW[768:1792] + b
    float sp = a * score_W[Dm + tid];
    if (tid < Dm) sp += text_v[tid] * score_W[tid];
    #pragma unroll
    for (int o = 32; o; o >>= 1) sp += __shfl_xor(sp, o);
    if ((tid & 63) == 0) sred[tid >> 6] = sp;
    __syncthreads();
    if (tid == 0) {
        float s = score_b[0];
        #pragma unroll
        for (int i = 0; i < 16; ++i) s += sred[i];
        out[0] = s;
    }
    // GRU
    const float gi_r = ws[WS_GI + tid];
    const float gi_z = ws[WS_GI + 1024 + tid];
    const float gi_n = ws[WS_GI + 2048 + tid];
    const float gh_r = ws[WS_GH + tid];
    const float gh_z = ws[WS_GH + 1024 + tid];
    const float gh_n = ws[WS_GH + 2048 + tid];
    const float hprev = hidden_s[(size_t)(LL - 1)*Hm + tid];
    const float r = 1.f / (1.f + expf(-(gi_r + gh_r)));
    const float z = 1.f / (1.f + expf(-(gi_z + gh_z)));
    const float n = tanhf(gi_n + r*gh_n);
    out[1 + tid] = (1.f - z)*n + z*hprev;
}

extern "C" void kernel_launch(void* const* d_in, const int* in_sizes, int n_in,
                              void* d_out, int out_size, void* d_ws, size_t ws_size,
                              hipStream_t stream) {
    const float* text_v   = (const float*)d_in[0];
    const float* result   = (const float*)d_in[1];
    const float* text_s   = (const float*)d_in[2];
    const float* hidden_s = (const float*)d_in[3];
    const float* W_ih     = (const float*)d_in[4];
    const float* W_hh     = (const float*)d_in[5];
    const float* b_ih     = (const float*)d_in[6];
    const float* b_hh     = (const float*)d_in[7];
    const float* score_W  = (const float*)d_in[8];
    const float* score_b  = (const float*)d_in[9];
    float* out = (float*)d_out;
    float* ws  = (float*)d_ws;

    k_main <<<ATT_B + GI_B + GH_B, 256, 0, stream>>>(
        text_v, result, text_s, hidden_s, W_ih, W_hh, b_ih, b_hh, ws);
    k_mid  <<<MID_B, 256, 0, stream>>>(ws);
    k_final<<<1, 1024, 0, stream>>>(text_v, hidden_s, score_W, score_b, ws, out);
}